// Round 1
// baseline (418.804 us; speedup 1.0000x reference)
//
#include <hip/hip_runtime.h>

#define NN 100000
#define EE 1600000
#define INC 128
#define OUTC 64
#define NEG_SLOPE 0.2f
#define CHUNK 391  // ceil(NN/256)

// ---------------- K1: Wx = x @ W^T, s_i = Wx·a[:64], s_j = Wx·a[64:] ----------------
// Block = 256 threads computes 256 rows x 64 cols. Thread (tc=t&7, tr=t>>3) owns
// rows {tr+32i} (stride-32 -> conflict-free LDS banks) x cols {tc+8j}.
__global__ __launch_bounds__(256) void k_gemm(
    const float* __restrict__ x, const float* __restrict__ W,
    const float* __restrict__ a, float* __restrict__ Wx,
    float* __restrict__ s_i, float* __restrict__ s_j)
{
  __shared__ __align__(16) float xs[256][20];   // 256 rows x 16-col chunk, pad 20
  __shared__ __align__(16) float Ws[64][132];   // full W, pad 132
  __shared__ float as[2 * OUTC];
  const int t = threadIdx.x;
  const int tc = t & 7;
  const int tr = t >> 3;
  const int row0 = blockIdx.x * 256;

  // stage W (64x128) via float4: 2048 float4 / 256 threads = 8 each
  #pragma unroll
  for (int i = 0; i < 8; ++i) {
    int idx = i * 256 + t;
    int r = idx >> 5;        // 32 float4 per row
    int c4 = idx & 31;
    float4 v = reinterpret_cast<const float4*>(W)[idx];
    *reinterpret_cast<float4*>(&Ws[r][c4 * 4]) = v;
  }
  if (t < 2 * OUTC) as[t] = a[t];

  float acc[8][8];
  #pragma unroll
  for (int i = 0; i < 8; ++i)
    #pragma unroll
    for (int j = 0; j < 8; ++j) acc[i][j] = 0.f;

  for (int k0 = 0; k0 < INC; k0 += 16) {
    __syncthreads();
    // stage x tile [256][16]: 1024 float4 / 256 threads = 4 each
    #pragma unroll
    for (int i = 0; i < 4; ++i) {
      int idx = i * 256 + t;
      int r = idx >> 2;      // 4 float4 per row
      int c4 = idx & 3;
      int gr = row0 + r;
      float4 v = make_float4(0.f, 0.f, 0.f, 0.f);
      if (gr < NN) v = *reinterpret_cast<const float4*>(&x[gr * INC + k0 + c4 * 4]);
      *reinterpret_cast<float4*>(&xs[r][c4 * 4]) = v;
    }
    __syncthreads();
    #pragma unroll
    for (int kk = 0; kk < 16; kk += 4) {
      float4 xv[8], wv[8];
      #pragma unroll
      for (int i = 0; i < 8; ++i)
        xv[i] = *reinterpret_cast<const float4*>(&xs[tr + 32 * i][kk]);
      #pragma unroll
      for (int j = 0; j < 8; ++j)
        wv[j] = *reinterpret_cast<const float4*>(&Ws[tc + 8 * j][k0 + kk]);
      #pragma unroll
      for (int i = 0; i < 8; ++i)
        #pragma unroll
        for (int j = 0; j < 8; ++j) {
          acc[i][j] = fmaf(xv[i].x, wv[j].x, acc[i][j]);
          acc[i][j] = fmaf(xv[i].y, wv[j].y, acc[i][j]);
          acc[i][j] = fmaf(xv[i].z, wv[j].z, acc[i][j]);
          acc[i][j] = fmaf(xv[i].w, wv[j].w, acc[i][j]);
        }
    }
  }

  // epilogue: write Wx + fused score dots (reduce over the 8-lane tc group)
  #pragma unroll
  for (int i = 0; i < 8; ++i) {
    int r = row0 + tr + 32 * i;
    float p1 = 0.f, p2 = 0.f;
    #pragma unroll
    for (int j = 0; j < 8; ++j) {
      int c = tc + 8 * j;
      if (r < NN) Wx[r * OUTC + c] = acc[i][j];
      p1 = fmaf(acc[i][j], as[c], p1);
      p2 = fmaf(acc[i][j], as[OUTC + c], p2);
    }
    #pragma unroll
    for (int m = 1; m < 8; m <<= 1) {
      p1 += __shfl_xor(p1, m);
      p2 += __shfl_xor(p2, m);
    }
    if (tc == 0 && r < NN) { s_i[r] = p1; s_j[r] = p2; }
  }
}

// ---------------- K2: degree histogram over dst ----------------
__global__ __launch_bounds__(256) void k_hist(const int* __restrict__ dst, int* __restrict__ deg) {
  int i = blockIdx.x * 256 + threadIdx.x;
  if (i < EE) atomicAdd(&deg[dst[i]], 1);
}

// ---------------- K3: exclusive scan of deg -> offsets (3 phases) ----------------
__global__ __launch_bounds__(256) void k_scan_partial(const int* __restrict__ deg, int* __restrict__ partial) {
  __shared__ int sd[256];
  int t = threadIdx.x, b = blockIdx.x;
  int base = b * CHUNK;
  int sum = 0;
  for (int i = t; i < CHUNK; i += 256) {
    int g = base + i;
    if (g < NN) sum += deg[g];
  }
  sd[t] = sum; __syncthreads();
  for (int s = 128; s > 0; s >>= 1) {
    if (t < s) sd[t] += sd[t + s];
    __syncthreads();
  }
  if (t == 0) partial[b] = sd[0];
}

__global__ __launch_bounds__(256) void k_scan_base(int* __restrict__ partial) {
  __shared__ int sd[256];
  int t = threadIdx.x;
  int v = partial[t];
  sd[t] = v; __syncthreads();
  for (int d = 1; d < 256; d <<= 1) {
    int u = (t >= d) ? sd[t - d] : 0;
    __syncthreads();
    sd[t] += u;
    __syncthreads();
  }
  partial[t] = sd[t] - v;  // exclusive
}

__global__ __launch_bounds__(512) void k_scan_final(const int* __restrict__ deg, const int* __restrict__ partial,
                                                    int* __restrict__ offsets, int* __restrict__ cursor) {
  __shared__ int sd[512];
  int t = threadIdx.x, b = blockIdx.x;
  int g = b * CHUNK + t;
  int v = (t < CHUNK && g < NN) ? deg[g] : 0;
  sd[t] = v; __syncthreads();
  for (int d = 1; d < 512; d <<= 1) {
    int u = (t >= d) ? sd[t - d] : 0;
    __syncthreads();
    sd[t] += u;
    __syncthreads();
  }
  int ex = sd[t] - v + partial[b];
  if (t < CHUNK && g < NN) { offsets[g] = ex; cursor[g] = ex; }
  if (b == 0 && t == 0) offsets[NN] = EE;
}

// ---------------- K4: bucket edges by dst (CSR build) ----------------
__global__ __launch_bounds__(256) void k_scatter(const int* __restrict__ src, const int* __restrict__ dst,
                                                 int* __restrict__ cursor, int* __restrict__ sorted) {
  int i = blockIdx.x * 256 + threadIdx.x;
  if (i < EE) {
    int pos = atomicAdd(&cursor[dst[i]], 1);
    sorted[pos] = src[i];
  }
}

// ---------------- K5: per-node softmax-weighted aggregation + ELU ----------------
// One wave per node; lane = output channel. No fp32 atomics anywhere.
// Max-shift elided: scores are O(8) so exp() is safe in fp32 and the result
// exp(e)/sum(exp(e)) is mathematically identical to the max-shifted form.
__global__ __launch_bounds__(256) void k_aggregate(const int* __restrict__ offsets, const int* __restrict__ sorted,
    const float* __restrict__ s_i, const float* __restrict__ s_j,
    const float* __restrict__ Wx, float* __restrict__ out)
{
  int n = blockIdx.x * 4 + (threadIdx.x >> 6);
  int lane = threadIdx.x & 63;
  if (n >= NN) return;
  int start = offsets[n], end = offsets[n + 1];
  float si = s_i[n];
  float acc = 0.f, den = 0.f;
  for (int idx = start; idx < end; ++idx) {
    int src = sorted[idx];
    float e = si + s_j[src];
    e = (e > 0.f) ? e : NEG_SLOPE * e;
    float w = __expf(e);
    den += w;
    acc = fmaf(w, Wx[src * OUTC + lane], acc);
  }
  float h = (den > 0.f) ? (acc / den) : 0.f;   // empty segment -> 0 (matches ref)
  out[n * OUTC + lane] = (h > 0.f) ? h : expm1f(h);
}

extern "C" void kernel_launch(void* const* d_in, const int* in_sizes, int n_in,
                              void* d_out, int out_size, void* d_ws, size_t ws_size,
                              hipStream_t stream) {
  const float* x = (const float*)d_in[0];
  const int* edge = (const int*)d_in[1];   // [2, E]: row 0 = src, row 1 = dst
  const float* W = (const float*)d_in[2];
  const float* a = (const float*)d_in[3];
  const int* srcIdx = edge;
  const int* dstIdx = edge + EE;
  float* out = (float*)d_out;

  // workspace layout (~34 MB)
  float* Wx = (float*)d_ws;                    // N*64 f32
  float* s_i = Wx + (size_t)NN * OUTC;         // N
  float* s_j = s_i + NN;                       // N
  int* deg = (int*)(s_j + NN);                 // N
  int* offsets = deg + NN;                     // N+1
  int* cursor = offsets + NN + 1;              // N
  int* partial = cursor + NN;                  // 256
  int* sorted = partial + 256;                 // E

  hipMemsetAsync(deg, 0, NN * sizeof(int), stream);
  k_gemm<<<(NN + 255) / 256, 256, 0, stream>>>(x, W, a, Wx, s_i, s_j);
  k_hist<<<(EE + 255) / 256, 256, 0, stream>>>(dstIdx, deg);
  k_scan_partial<<<256, 256, 0, stream>>>(deg, partial);
  k_scan_base<<<1, 256, 0, stream>>>(partial);
  k_scan_final<<<256, 512, 0, stream>>>(deg, partial, offsets, cursor);
  k_scatter<<<(EE + 255) / 256, 256, 0, stream>>>(srcIdx, dstIdx, cursor, sorted);
  k_aggregate<<<(NN + 3) / 4, 256, 0, stream>>>(offsets, sorted, s_i, s_j, Wx, out);
}

// Round 2
// 329.591 us; speedup vs baseline: 1.2707x; 1.2707x over previous
//
#include <hip/hip_runtime.h>

#define NN 100000
#define EE 1600000
#define INC 128
#define OUTC 64
#define NEG_SLOPE 0.2f
#define CHUNK 391  // ceil(NN/256)

__device__ __forceinline__ unsigned short f2bf(float f) {
  unsigned u = __float_as_uint(f);
  unsigned r = (u + 0x7fffu + ((u >> 16) & 1u)) >> 16;  // RNE
  return (unsigned short)r;
}
__device__ __forceinline__ float bf2f(unsigned short h) {
  return __uint_as_float(((unsigned)h) << 16);
}

// ---------------- K1: Wx = x @ W^T (bf16 out), s_i = Wx·a[:64], s_j = Wx·a[64:] ----
// Block = 256 threads computes 256 rows x 64 cols. Thread (tc=t&7, tr=t>>3) owns
// rows {tr+32i} x cols {tc+8j} (both stride patterns LDS-conflict-free).
__global__ __launch_bounds__(256) void k_gemm(
    const float* __restrict__ x, const float* __restrict__ W,
    const float* __restrict__ a, unsigned short* __restrict__ Wxh,
    float* __restrict__ s_i, float* __restrict__ s_j)
{
  __shared__ __align__(16) float xs[256][20];   // x tile, pad 20 (conflict-free)
  __shared__ __align__(16) float Ws[64][132];   // full W, pad 132 (conflict-free)
  __shared__ float as[2 * OUTC];
  __shared__ __align__(16) unsigned short hs[64][80];  // bf16 bounce, row=160B (16B-aligned)
  const int t = threadIdx.x;
  const int tc = t & 7;
  const int tr = t >> 3;
  const int row0 = blockIdx.x * 256;

  // stage W (64x128) via float4: 2048 float4 / 256 threads = 8 each
  #pragma unroll
  for (int i = 0; i < 8; ++i) {
    int idx = i * 256 + t;
    int r = idx >> 5;
    int c4 = idx & 31;
    float4 v = reinterpret_cast<const float4*>(W)[idx];
    *reinterpret_cast<float4*>(&Ws[r][c4 * 4]) = v;
  }
  if (t < 2 * OUTC) as[t] = a[t];

  float acc[8][8];
  #pragma unroll
  for (int i = 0; i < 8; ++i)
    #pragma unroll
    for (int j = 0; j < 8; ++j) acc[i][j] = 0.f;

  for (int k0 = 0; k0 < INC; k0 += 16) {
    __syncthreads();
    #pragma unroll
    for (int i = 0; i < 4; ++i) {
      int idx = i * 256 + t;
      int r = idx >> 2;
      int c4 = idx & 3;
      int gr = row0 + r;
      float4 v = make_float4(0.f, 0.f, 0.f, 0.f);
      if (gr < NN) v = *reinterpret_cast<const float4*>(&x[gr * INC + k0 + c4 * 4]);
      *reinterpret_cast<float4*>(&xs[r][c4 * 4]) = v;
    }
    __syncthreads();
    #pragma unroll
    for (int kk = 0; kk < 16; kk += 4) {
      float4 xv[8], wv[8];
      #pragma unroll
      for (int i = 0; i < 8; ++i)
        xv[i] = *reinterpret_cast<const float4*>(&xs[tr + 32 * i][kk]);
      #pragma unroll
      for (int j = 0; j < 8; ++j)
        wv[j] = *reinterpret_cast<const float4*>(&Ws[tc + 8 * j][k0 + kk]);
      #pragma unroll
      for (int i = 0; i < 8; ++i)
        #pragma unroll
        for (int j = 0; j < 8; ++j) {
          acc[i][j] = fmaf(xv[i].x, wv[j].x, acc[i][j]);
          acc[i][j] = fmaf(xv[i].y, wv[j].y, acc[i][j]);
          acc[i][j] = fmaf(xv[i].z, wv[j].z, acc[i][j]);
          acc[i][j] = fmaf(xv[i].w, wv[j].w, acc[i][j]);
        }
    }
  }

  // fused score dots (reduce over the 8-lane tc group)
  #pragma unroll
  for (int i = 0; i < 8; ++i) {
    int r = row0 + tr + 32 * i;
    float p1 = 0.f, p2 = 0.f;
    #pragma unroll
    for (int j = 0; j < 8; ++j) {
      int c = tc + 8 * j;
      p1 = fmaf(acc[i][j], as[c], p1);
      p2 = fmaf(acc[i][j], as[OUTC + c], p2);
    }
    #pragma unroll
    for (int m = 1; m < 8; m <<= 1) {
      p1 += __shfl_xor(p1, m);
      p2 += __shfl_xor(p2, m);
    }
    if (tc == 0 && r < NN) { s_i[r] = p1; s_j[r] = p2; }
  }

  // bf16 Wx store via LDS bounce, 4 chunks of 64 rows -> coalesced uint4 stores
  #pragma unroll
  for (int c = 0; c < 4; ++c) {
    __syncthreads();
    #pragma unroll
    for (int ii = 0; ii < 2; ++ii) {
      int lr = tr + 32 * ii;
      #pragma unroll
      for (int j = 0; j < 8; ++j)
        hs[lr][tc + 8 * j] = f2bf(acc[2 * c + ii][j]);
    }
    __syncthreads();
    #pragma unroll
    for (int k = 0; k < 2; ++k) {
      int idx = k * 256 + t;
      int rr = idx >> 3;      // 8 uint4 per 64-col bf16 row
      int c8 = idx & 7;
      int gr = row0 + 64 * c + rr;
      if (gr < NN) {
        uint4 v = *reinterpret_cast<const uint4*>(&hs[rr][c8 * 8]);
        *reinterpret_cast<uint4*>(&Wxh[(size_t)gr * OUTC + c8 * 8]) = v;
      }
    }
  }
}

// ---------------- K2: degree histogram over dst (4 edges/thread) ----------------
__global__ __launch_bounds__(256) void k_hist(const int* __restrict__ dst, int* __restrict__ deg) {
  int i = blockIdx.x * 256 + threadIdx.x;
  if (i < EE / 4) {
    int4 d = reinterpret_cast<const int4*>(dst)[i];
    atomicAdd(&deg[d.x], 1);
    atomicAdd(&deg[d.y], 1);
    atomicAdd(&deg[d.z], 1);
    atomicAdd(&deg[d.w], 1);
  }
}

// ---------------- K3: exclusive scan of deg -> offsets (3 phases) ----------------
__global__ __launch_bounds__(256) void k_scan_partial(const int* __restrict__ deg, int* __restrict__ partial) {
  __shared__ int sd[256];
  int t = threadIdx.x, b = blockIdx.x;
  int base = b * CHUNK;
  int sum = 0;
  for (int i = t; i < CHUNK; i += 256) {
    int g = base + i;
    if (g < NN) sum += deg[g];
  }
  sd[t] = sum; __syncthreads();
  for (int s = 128; s > 0; s >>= 1) {
    if (t < s) sd[t] += sd[t + s];
    __syncthreads();
  }
  if (t == 0) partial[b] = sd[0];
}

__global__ __launch_bounds__(256) void k_scan_base(int* __restrict__ partial) {
  __shared__ int sd[256];
  int t = threadIdx.x;
  int v = partial[t];
  sd[t] = v; __syncthreads();
  for (int d = 1; d < 256; d <<= 1) {
    int u = (t >= d) ? sd[t - d] : 0;
    __syncthreads();
    sd[t] += u;
    __syncthreads();
  }
  partial[t] = sd[t] - v;  // exclusive
}

__global__ __launch_bounds__(512) void k_scan_final(const int* __restrict__ deg, const int* __restrict__ partial,
                                                    int* __restrict__ offsets, int* __restrict__ cursor) {
  __shared__ int sd[512];
  int t = threadIdx.x, b = blockIdx.x;
  int g = b * CHUNK + t;
  int v = (t < CHUNK && g < NN) ? deg[g] : 0;
  sd[t] = v; __syncthreads();
  for (int d = 1; d < 512; d <<= 1) {
    int u = (t >= d) ? sd[t - d] : 0;
    __syncthreads();
    sd[t] += u;
    __syncthreads();
  }
  int ex = sd[t] - v + partial[b];
  if (t < CHUNK && g < NN) { offsets[g] = ex; cursor[g] = ex; }
  if (b == 0 && t == 0) offsets[NN] = EE;
}

// ---------------- K4: bucket edges by dst (CSR build, 4 edges/thread) ----------------
__global__ __launch_bounds__(256) void k_scatter(const int* __restrict__ src, const int* __restrict__ dst,
                                                 int* __restrict__ cursor, int* __restrict__ sorted) {
  int i = blockIdx.x * 256 + threadIdx.x;
  if (i < EE / 4) {
    int4 s = reinterpret_cast<const int4*>(src)[i];
    int4 d = reinterpret_cast<const int4*>(dst)[i];
    int p0 = atomicAdd(&cursor[d.x], 1); sorted[p0] = s.x;
    int p1 = atomicAdd(&cursor[d.y], 1); sorted[p1] = s.y;
    int p2 = atomicAdd(&cursor[d.z], 1); sorted[p2] = s.z;
    int p3 = atomicAdd(&cursor[d.w], 1); sorted[p3] = s.w;
  }
}

// ---------------- K5: per-node softmax aggregation + ELU ----------------
// One wave per node. 4 groups of 16 lanes: group g handles edges base+g and
// base+4+g (8 independent gathers in flight); lane holds 4 channels (8B bf16
// vector load). Cross-group shfl_xor(16,32) reduce at the end. No fp32 atomics.
// Max-shift elided: scores are O(10) so exp() is safe in fp32; exp(e)/sum(exp(e))
// is mathematically identical to the max-shifted form.
__global__ __launch_bounds__(256) void k_aggregate(
    const int* __restrict__ offsets, const int* __restrict__ sorted,
    const float* __restrict__ s_i, const float* __restrict__ s_j,
    const unsigned short* __restrict__ Wxh, float* __restrict__ out)
{
  int n = blockIdx.x * 4 + (threadIdx.x >> 6);
  if (n >= NN) return;
  int lane = threadIdx.x & 63;
  int g = lane >> 4;        // edge slot 0..3
  int cl = lane & 15;       // channel quad: channels 4*cl..4*cl+3
  int start = offsets[n], end = offsets[n + 1];
  float si = s_i[n];
  float ax = 0.f, ay = 0.f, az = 0.f, aw = 0.f, den = 0.f;

  for (int base = start; base < end; base += 8) {
    int i0 = base + g;
    int i1 = base + 4 + g;
    bool v0 = i0 < end, v1 = i1 < end;
    int src0 = v0 ? sorted[i0] : 0;
    int src1 = v1 ? sorted[i1] : 0;
    ushort4 h0 = *reinterpret_cast<const ushort4*>(&Wxh[(size_t)src0 * OUTC + 4 * cl]);
    ushort4 h1 = *reinterpret_cast<const ushort4*>(&Wxh[(size_t)src1 * OUTC + 4 * cl]);
    float e0 = si + s_j[src0];
    float e1 = si + s_j[src1];
    e0 = (e0 > 0.f) ? e0 : NEG_SLOPE * e0;
    e1 = (e1 > 0.f) ? e1 : NEG_SLOPE * e1;
    float w0 = v0 ? __expf(e0) : 0.f;
    float w1 = v1 ? __expf(e1) : 0.f;
    den += w0 + w1;
    ax = fmaf(w0, bf2f(h0.x), ax);
    ay = fmaf(w0, bf2f(h0.y), ay);
    az = fmaf(w0, bf2f(h0.z), az);
    aw = fmaf(w0, bf2f(h0.w), aw);
    ax = fmaf(w1, bf2f(h1.x), ax);
    ay = fmaf(w1, bf2f(h1.y), ay);
    az = fmaf(w1, bf2f(h1.z), az);
    aw = fmaf(w1, bf2f(h1.w), aw);
  }

  #pragma unroll
  for (int m = 16; m <= 32; m <<= 1) {
    ax += __shfl_xor(ax, m);
    ay += __shfl_xor(ay, m);
    az += __shfl_xor(az, m);
    aw += __shfl_xor(aw, m);
    den += __shfl_xor(den, m);
  }

  if (g == 0) {
    float inv = (den > 0.f) ? 1.f / den : 0.f;  // empty segment -> 0 (matches ref)
    float4 r;
    r.x = ax * inv; r.y = ay * inv; r.z = az * inv; r.w = aw * inv;
    r.x = (r.x > 0.f) ? r.x : expm1f(r.x);
    r.y = (r.y > 0.f) ? r.y : expm1f(r.y);
    r.z = (r.z > 0.f) ? r.z : expm1f(r.z);
    r.w = (r.w > 0.f) ? r.w : expm1f(r.w);
    *reinterpret_cast<float4*>(&out[(size_t)n * OUTC + 4 * cl]) = r;
  }
}

extern "C" void kernel_launch(void* const* d_in, const int* in_sizes, int n_in,
                              void* d_out, int out_size, void* d_ws, size_t ws_size,
                              hipStream_t stream) {
  const float* x = (const float*)d_in[0];
  const int* edge = (const int*)d_in[1];   // [2, E]: row 0 = src, row 1 = dst
  const float* W = (const float*)d_in[2];
  const float* a = (const float*)d_in[3];
  const int* srcIdx = edge;
  const int* dstIdx = edge + EE;
  float* out = (float*)d_out;

  // workspace layout (~22 MB)
  unsigned short* Wxh = (unsigned short*)d_ws;   // N*64 bf16
  float* s_i = (float*)(Wxh + (size_t)NN * OUTC);  // N
  float* s_j = s_i + NN;                       // N
  int* deg = (int*)(s_j + NN);                 // N
  int* offsets = deg + NN;                     // N+1
  int* cursor = offsets + NN + 1;              // N
  int* partial = cursor + NN;                  // 256
  int* sorted = partial + 256;                 // E

  hipMemsetAsync(deg, 0, NN * sizeof(int), stream);
  k_gemm<<<(NN + 255) / 256, 256, 0, stream>>>(x, W, a, Wxh, s_i, s_j);
  k_hist<<<(EE / 4 + 255) / 256, 256, 0, stream>>>(dstIdx, deg);
  k_scan_partial<<<256, 256, 0, stream>>>(deg, partial);
  k_scan_base<<<1, 256, 0, stream>>>(partial);
  k_scan_final<<<256, 512, 0, stream>>>(deg, partial, offsets, cursor);
  k_scatter<<<(EE / 4 + 255) / 256, 256, 0, stream>>>(srcIdx, dstIdx, cursor, sorted);
  k_aggregate<<<(NN + 3) / 4, 256, 0, stream>>>(offsets, sorted, s_i, s_j, Wxh, out);
}